// Round 6
// baseline (2584.105 us; speedup 1.0000x reference)
//
#include <hip/hip_runtime.h>
#include <math.h>

#define ND 256
#define RPB 64            // rows per block; lane = row
#define ROWS_PER_B 576    // 24*24 perm pairs per batch elem
#define BATCH 512
#define BPE 9             // blocks per batch elem (576/64)
#define NBLOCKS (BATCH * BPE)   // 4608

// itertools.permutations(range(4)) — lexicographic order, with parity signs
__constant__ int c_P[24 * 4] = {
    0,1,2,3, 0,1,3,2, 0,2,1,3, 0,2,3,1, 0,3,1,2, 0,3,2,1,
    1,0,2,3, 1,0,3,2, 1,2,0,3, 1,2,3,0, 1,3,0,2, 1,3,2,0,
    2,0,1,3, 2,0,3,1, 2,1,0,3, 2,1,3,0, 2,3,0,1, 2,3,1,0,
    3,0,1,2, 3,0,2,1, 3,1,0,2, 3,1,2,0, 3,2,0,1, 3,2,1,0
};
__constant__ float c_S[24] = {
     1.f,-1.f,-1.f, 1.f, 1.f,-1.f,
    -1.f, 1.f, 1.f,-1.f,-1.f, 1.f,
     1.f,-1.f,-1.f, 1.f, 1.f,-1.f,
    -1.f, 1.f, 1.f,-1.f,-1.f, 1.f
};

__global__ __launch_bounds__(256, 2)
void fused_resnet(const float* __restrict__ x1, const float* __restrict__ x2,
                  const float* __restrict__ W0, const float* __restrict__ b0,
                  const float* __restrict__ W1, const float* __restrict__ b1,
                  const float* __restrict__ W2, const float* __restrict__ b2,
                  const float* __restrict__ Wf, const float* __restrict__ bf,
                  double* __restrict__ anti)
{
    // Transposed activations: sYT[c][row], row = lane -> stride-1, conflict-free
    __shared__ float sYT[ND * RPB];   // 64 KB
    const int t    = threadIdx.x;
    const int lane = t & 63;          // = row within block
    const int wid  = t >> 6;
    // col base for this wave — force wave-uniform so W loads scalarize (s_load)
    const int cb   = __builtin_amdgcn_readfirstlane(wid << 6);
    const int b    = blockIdx.x / BPE;
    const int pp   = (blockIdx.x % BPE) * RPB + lane;   // perm-pair index 0..575
    const int p1   = pp / 24, p2 = pp % 24;

    // ---- per-lane features in registers (row = lane) ----
    float feats[24];
    #pragma unroll
    for (int i = 0; i < 4; ++i)
        #pragma unroll
        for (int d = 0; d < 3; ++d) {
            feats[i * 3 + d]      = x1[b * 12 + c_P[p1 * 4 + i] * 3 + d];
            feats[12 + i * 3 + d] = x2[b * 12 + c_P[p2 * 4 + i] * 3 + d];
        }

    float acc[64], yprev[64];

    // ---------- layer 0: 24 -> 256 (this wave's 64 cols), k ascending ----------
    #pragma unroll
    for (int j = 0; j < 64; ++j) acc[j] = 0.f;
    #pragma unroll 1
    for (int k = 0; k < 24; ++k) {
        const float* wk = W0 + k * ND + cb;   // wave-uniform -> s_load
        float yk = feats[k];                  // register
        #pragma unroll
        for (int j = 0; j < 64; ++j) acc[j] = fmaf(yk, wk[j], acc[j]);
    }
    #pragma unroll
    for (int j = 0; j < 64; ++j) {
        yprev[j] = tanhf(acc[j] + b0[cb + j]);
        sYT[(cb + j) * RPB + lane] = yprev[j];
    }
    __syncthreads();

    // ---------- layers 1,2: 256 -> 256, tanh + residual ----------
    #pragma unroll 1
    for (int layer = 0; layer < 2; ++layer) {
        const float* W  = layer ? W2 : W1;
        const float* bb = layer ? b2 : b1;
        #pragma unroll
        for (int j = 0; j < 64; ++j) acc[j] = 0.f;
        #pragma unroll 2
        for (int k = 0; k < ND; ++k) {
            float yk = sYT[k * RPB + lane];   // 1 conflict-free ds_read_b32 per k
            const float* wk = W + k * ND + cb; // wave-uniform -> s_load
            #pragma unroll
            for (int j = 0; j < 64; ++j) acc[j] = fmaf(yk, wk[j], acc[j]);
        }
        __syncthreads();   // all waves done READING sYT before overwrite
        #pragma unroll
        for (int j = 0; j < 64; ++j) {
            float ny = tanhf(acc[j] + bb[cb + j]) + yprev[j];
            yprev[j] = ny;
            sYT[(cb + j) * RPB + lane] = ny;
        }
        __syncthreads();   // new sYT visible to all waves
    }

    // ---------- head: wave 0, lane = row; sequential fp32 chain over k ----------
    if (wid == 0) {
        float f = 0.f;
        #pragma unroll 1
        for (int k = 0; k < ND; ++k)
            f = fmaf(sYT[k * RPB + lane], Wf[k], f);   // Wf[k] uniform -> s_load
        f += bf[0];
        double contrib = (double)(c_S[p1] * c_S[p2]) * (double)f;
        #pragma unroll
        for (int off = 32; off > 0; off >>= 1) contrib += __shfl_xor(contrib, off, 64);
        if (lane == 0) atomicAdd(&anti[b], contrib);
    }
}

__global__ void finalize_log(const double* __restrict__ anti, float* __restrict__ out) {
    int i = blockIdx.x * 256 + threadIdx.x;
    if (i < BATCH) out[i] = (float)log(fabs(anti[i]));
}

extern "C" void kernel_launch(void* const* d_in, const int* in_sizes, int n_in,
                              void* d_out, int out_size, void* d_ws, size_t ws_size,
                              hipStream_t stream) {
    const float* x1 = (const float*)d_in[0];
    const float* x2 = (const float*)d_in[1];
    const float* W0 = (const float*)d_in[2];
    const float* b0 = (const float*)d_in[3];
    const float* W1 = (const float*)d_in[4];
    const float* b1 = (const float*)d_in[5];
    const float* W2 = (const float*)d_in[6];
    const float* b2 = (const float*)d_in[7];
    const float* Wf = (const float*)d_in[8];
    const float* bf = (const float*)d_in[9];
    double* anti = (double*)d_ws;                   // 512 doubles of scratch
    float* out   = (float*)d_out;

    hipMemsetAsync(anti, 0, BATCH * sizeof(double), stream);
    fused_resnet<<<NBLOCKS, 256, 0, stream>>>(x1, x2, W0, b0, W1, b1, W2, b2, Wf, bf, anti);
    finalize_log<<<(BATCH + 255) / 256, 256, 0, stream>>>(anti, out);
}

// Round 7
// 1497.008 us; speedup vs baseline: 1.7262x; 1.7262x over previous
//
#include <hip/hip_runtime.h>
#include <math.h>

#define ND 256
#define RPB 64            // rows per block; lane = row
#define CPT 32            // cols per thread (wave covers 32 cols)
#define ROWS_PER_B 576    // 24*24 perm pairs per batch elem
#define BATCH 512
#define BPE 9             // blocks per batch elem (576/64)
#define NBLOCKS (BATCH * BPE)   // 4608

// itertools.permutations(range(4)) — lexicographic order, with parity signs
__constant__ int c_P[24 * 4] = {
    0,1,2,3, 0,1,3,2, 0,2,1,3, 0,2,3,1, 0,3,1,2, 0,3,2,1,
    1,0,2,3, 1,0,3,2, 1,2,0,3, 1,2,3,0, 1,3,0,2, 1,3,2,0,
    2,0,1,3, 2,0,3,1, 2,1,0,3, 2,1,3,0, 2,3,0,1, 2,3,1,0,
    3,0,1,2, 3,0,2,1, 3,1,0,2, 3,1,2,0, 3,2,0,1, 3,2,1,0
};
__constant__ float c_S[24] = {
     1.f,-1.f,-1.f, 1.f, 1.f,-1.f,
    -1.f, 1.f, 1.f,-1.f,-1.f, 1.f,
     1.f,-1.f,-1.f, 1.f, 1.f,-1.f,
    -1.f, 1.f, 1.f,-1.f,-1.f, 1.f
};

__global__ __launch_bounds__(512, 4)
void fused_resnet(const float* __restrict__ x1, const float* __restrict__ x2,
                  const float* __restrict__ W0, const float* __restrict__ b0,
                  const float* __restrict__ W1, const float* __restrict__ b1,
                  const float* __restrict__ W2, const float* __restrict__ b2,
                  const float* __restrict__ Wf, const float* __restrict__ bf,
                  double* __restrict__ anti)
{
    // Transposed activations: sYT[c][row], row = lane -> stride-1, conflict-free
    __shared__ float sYT[ND * RPB];   // 64 KB
    const int t    = threadIdx.x;
    const int lane = t & 63;          // = row within block
    const int wid  = t >> 6;          // 0..7
    // col base for this wave — wave-uniform so W loads scalarize (s_load)
    const int cb   = __builtin_amdgcn_readfirstlane(wid << 5);
    const int b    = blockIdx.x / BPE;
    const int pp   = (blockIdx.x % BPE) * RPB + lane;   // perm-pair index 0..575
    const int p1   = pp / 24, p2 = pp % 24;

    // ---- per-lane features in registers (row = lane) ----
    float feats[24];
    #pragma unroll
    for (int i = 0; i < 4; ++i)
        #pragma unroll
        for (int d = 0; d < 3; ++d) {
            feats[i * 3 + d]      = x1[b * 12 + c_P[p1 * 4 + i] * 3 + d];
            feats[12 + i * 3 + d] = x2[b * 12 + c_P[p2 * 4 + i] * 3 + d];
        }

    float acc[CPT], yprev[CPT];   // 64 VGPRs — fits without AGPR spill

    // ---------- layer 0: 24 -> 256 (this wave's 32 cols), k ascending ----------
    #pragma unroll
    for (int j = 0; j < CPT; ++j) acc[j] = 0.f;
    #pragma unroll 2
    for (int k = 0; k < 24; ++k) {
        const float* wk = W0 + k * ND + cb;   // wave-uniform -> s_load
        float yk = feats[k];                  // register
        #pragma unroll
        for (int j = 0; j < CPT; ++j) acc[j] = fmaf(yk, wk[j], acc[j]);
    }
    #pragma unroll
    for (int j = 0; j < CPT; ++j) {
        yprev[j] = tanhf(acc[j] + b0[cb + j]);
        sYT[(cb + j) * RPB + lane] = yprev[j];
    }
    __syncthreads();

    // ---------- layers 1,2: 256 -> 256, tanh + residual ----------
    #pragma unroll 1
    for (int layer = 0; layer < 2; ++layer) {
        const float* W  = layer ? W2 : W1;
        const float* bb = layer ? b2 : b1;
        #pragma unroll
        for (int j = 0; j < CPT; ++j) acc[j] = 0.f;
        #pragma unroll 2
        for (int k = 0; k < ND; ++k) {
            float yk = sYT[k * RPB + lane];    // 1 conflict-free ds_read_b32 per k
            const float* wk = W + k * ND + cb; // wave-uniform -> s_load (32 floats)
            #pragma unroll
            for (int j = 0; j < CPT; ++j) acc[j] = fmaf(yk, wk[j], acc[j]);
        }
        __syncthreads();   // all waves done READING sYT before overwrite
        #pragma unroll
        for (int j = 0; j < CPT; ++j) {
            float ny = tanhf(acc[j] + bb[cb + j]) + yprev[j];
            yprev[j] = ny;
            sYT[(cb + j) * RPB + lane] = ny;
        }
        __syncthreads();   // new sYT visible to all waves
    }

    // ---------- head: wave 0, lane = row; sequential fp32 chain over k ----------
    if (wid == 0) {
        float f = 0.f;
        #pragma unroll 1
        for (int k = 0; k < ND; ++k)
            f = fmaf(sYT[k * RPB + lane], Wf[k], f);   // Wf[k] uniform -> s_load
        f += bf[0];
        double contrib = (double)(c_S[p1] * c_S[p2]) * (double)f;
        #pragma unroll
        for (int off = 32; off > 0; off >>= 1) contrib += __shfl_xor(contrib, off, 64);
        if (lane == 0) atomicAdd(&anti[b], contrib);
    }
}

__global__ void finalize_log(const double* __restrict__ anti, float* __restrict__ out) {
    int i = blockIdx.x * 256 + threadIdx.x;
    if (i < BATCH) out[i] = (float)log(fabs(anti[i]));
}

extern "C" void kernel_launch(void* const* d_in, const int* in_sizes, int n_in,
                              void* d_out, int out_size, void* d_ws, size_t ws_size,
                              hipStream_t stream) {
    const float* x1 = (const float*)d_in[0];
    const float* x2 = (const float*)d_in[1];
    const float* W0 = (const float*)d_in[2];
    const float* b0 = (const float*)d_in[3];
    const float* W1 = (const float*)d_in[4];
    const float* b1 = (const float*)d_in[5];
    const float* W2 = (const float*)d_in[6];
    const float* b2 = (const float*)d_in[7];
    const float* Wf = (const float*)d_in[8];
    const float* bf = (const float*)d_in[9];
    double* anti = (double*)d_ws;                   // 512 doubles of scratch
    float* out   = (float*)d_out;

    hipMemsetAsync(anti, 0, BATCH * sizeof(double), stream);
    fused_resnet<<<NBLOCKS, 512, 0, stream>>>(x1, x2, W0, b0, W1, b1, W2, b2, Wf, bf, anti);
    finalize_log<<<(BATCH + 255) / 256, 256, 0, stream>>>(anti, out);
}

// Round 8
// 1406.022 us; speedup vs baseline: 1.8379x; 1.0647x over previous
//
#include <hip/hip_runtime.h>
#include <math.h>

#define ND 256
#define RPB 64            // rows per block; lane = row
#define CPT 16            // cols per thread (wave covers 16 cols)
#define ROWS_PER_B 576    // 24*24 perm pairs per batch elem
#define BATCH 512
#define BPE 9             // blocks per batch elem (576/64)
#define NBLOCKS (BATCH * BPE)   // 4608

// itertools.permutations(range(4)) — lexicographic order, with parity signs
__constant__ int c_P[24 * 4] = {
    0,1,2,3, 0,1,3,2, 0,2,1,3, 0,2,3,1, 0,3,1,2, 0,3,2,1,
    1,0,2,3, 1,0,3,2, 1,2,0,3, 1,2,3,0, 1,3,0,2, 1,3,2,0,
    2,0,1,3, 2,0,3,1, 2,1,0,3, 2,1,3,0, 2,3,0,1, 2,3,1,0,
    3,0,1,2, 3,0,2,1, 3,1,0,2, 3,1,2,0, 3,2,0,1, 3,2,1,0
};
__constant__ float c_S[24] = {
     1.f,-1.f,-1.f, 1.f, 1.f,-1.f,
    -1.f, 1.f, 1.f,-1.f,-1.f, 1.f,
     1.f,-1.f,-1.f, 1.f, 1.f,-1.f,
    -1.f, 1.f, 1.f,-1.f,-1.f, 1.f
};

__global__ __launch_bounds__(1024, 8)
void fused_resnet(const float* __restrict__ x1, const float* __restrict__ x2,
                  const float* __restrict__ W0, const float* __restrict__ b0,
                  const float* __restrict__ W1, const float* __restrict__ b1,
                  const float* __restrict__ W2, const float* __restrict__ b2,
                  const float* __restrict__ Wf, const float* __restrict__ bf,
                  double* __restrict__ anti)
{
    // Transposed activations: sYT[c][row], row = lane -> stride-1, conflict-free
    __shared__ float sYT[ND * RPB];   // 64 KB -> 2 blocks/CU -> 32 waves/CU (100%)
    const int t    = threadIdx.x;
    const int lane = t & 63;          // = row within block
    const int wid  = t >> 6;          // 0..15
    // col base for this wave — wave-uniform so W loads scalarize (s_load)
    const int cb   = __builtin_amdgcn_readfirstlane(wid << 4);
    const int b    = blockIdx.x / BPE;
    const int pp   = (blockIdx.x % BPE) * RPB + lane;   // perm-pair index 0..575
    const int p1   = pp / 24, p2 = pp % 24;

    // ---- per-lane features in registers (row = lane) ----
    float feats[24];
    #pragma unroll
    for (int i = 0; i < 4; ++i)
        #pragma unroll
        for (int d = 0; d < 3; ++d) {
            feats[i * 3 + d]      = x1[b * 12 + c_P[p1 * 4 + i] * 3 + d];
            feats[12 + i * 3 + d] = x2[b * 12 + c_P[p2 * 4 + i] * 3 + d];
        }

    float acc[CPT], yprev[CPT];   // 32 VGPRs — fits 8-waves/SIMD budget (64)

    // ---------- layer 0: 24 -> 256 (this wave's 16 cols), k ascending ----------
    #pragma unroll
    for (int j = 0; j < CPT; ++j) acc[j] = 0.f;
    #pragma unroll 4
    for (int k = 0; k < 24; ++k) {
        const float* wk = W0 + k * ND + cb;   // wave-uniform -> s_load
        float yk = feats[k];                  // register
        #pragma unroll
        for (int j = 0; j < CPT; ++j) acc[j] = fmaf(yk, wk[j], acc[j]);
    }
    #pragma unroll
    for (int j = 0; j < CPT; ++j) {
        yprev[j] = tanhf(acc[j] + b0[cb + j]);
        sYT[(cb + j) * RPB + lane] = yprev[j];
    }
    __syncthreads();

    // ---------- layers 1,2: 256 -> 256, tanh + residual ----------
    #pragma unroll 1
    for (int layer = 0; layer < 2; ++layer) {
        const float* W  = layer ? W2 : W1;
        const float* bb = layer ? b2 : b1;
        #pragma unroll
        for (int j = 0; j < CPT; ++j) acc[j] = 0.f;
        #pragma unroll 4
        for (int k = 0; k < ND; ++k) {
            float yk = sYT[k * RPB + lane];    // 1 conflict-free ds_read_b32 per k
            const float* wk = W + k * ND + cb; // wave-uniform -> s_load (16 floats)
            #pragma unroll
            for (int j = 0; j < CPT; ++j) acc[j] = fmaf(yk, wk[j], acc[j]);
        }
        __syncthreads();   // all waves done READING sYT before overwrite
        #pragma unroll
        for (int j = 0; j < CPT; ++j) {
            float ny = tanhf(acc[j] + bb[cb + j]) + yprev[j];
            yprev[j] = ny;
            sYT[(cb + j) * RPB + lane] = ny;
        }
        __syncthreads();   // new sYT visible to all waves
    }

    // ---------- head: wave 0, lane = row; sequential fp32 chain over k ----------
    if (wid == 0) {
        float f = 0.f;
        #pragma unroll 1
        for (int k = 0; k < ND; ++k)
            f = fmaf(sYT[k * RPB + lane], Wf[k], f);   // Wf[k] uniform -> s_load
        f += bf[0];
        double contrib = (double)(c_S[p1] * c_S[p2]) * (double)f;
        #pragma unroll
        for (int off = 32; off > 0; off >>= 1) contrib += __shfl_xor(contrib, off, 64);
        if (lane == 0) atomicAdd(&anti[b], contrib);
    }
}

__global__ void finalize_log(const double* __restrict__ anti, float* __restrict__ out) {
    int i = blockIdx.x * 256 + threadIdx.x;
    if (i < BATCH) out[i] = (float)log(fabs(anti[i]));
}

extern "C" void kernel_launch(void* const* d_in, const int* in_sizes, int n_in,
                              void* d_out, int out_size, void* d_ws, size_t ws_size,
                              hipStream_t stream) {
    const float* x1 = (const float*)d_in[0];
    const float* x2 = (const float*)d_in[1];
    const float* W0 = (const float*)d_in[2];
    const float* b0 = (const float*)d_in[3];
    const float* W1 = (const float*)d_in[4];
    const float* b1 = (const float*)d_in[5];
    const float* W2 = (const float*)d_in[6];
    const float* b2 = (const float*)d_in[7];
    const float* Wf = (const float*)d_in[8];
    const float* bf = (const float*)d_in[9];
    double* anti = (double*)d_ws;                   // 512 doubles of scratch
    float* out   = (float*)d_out;

    hipMemsetAsync(anti, 0, BATCH * sizeof(double), stream);
    fused_resnet<<<NBLOCKS, 1024, 0, stream>>>(x1, x2, W0, b0, W1, b1, W2, b2, Wf, bf, anti);
    finalize_log<<<(BATCH + 255) / 256, 256, 0, stream>>>(anti, out);
}